// Round 2
// baseline (997.557 us; speedup 1.0000x reference)
//
#include <hip/hip_runtime.h>

#define NN 100000
#define NE 1000000
#define NG 2048
#define HD 64
#define NBLK 98  // ceil(NN/1024)

// ---------------- graph preprocessing ----------------

__global__ void k_deg(const int* __restrict__ dst, int* __restrict__ cnt, int E) {
    int i = blockIdx.x * blockDim.x + threadIdx.x;
    if (i < E) atomicAdd(&cnt[dst[i]], 1);
}

// pass 1: per-block (1024 elems) sums. 256 thr x int4.
__global__ void k_scan1(const int* __restrict__ cnt, int* __restrict__ bsum, int n) {
    int t = threadIdx.x;
    int base = blockIdx.x * 1024 + t * 4;
    int4 v = {0, 0, 0, 0};
    if (base < n) v = *(const int4*)(cnt + base);  // n % 4 == 0 so base<n => base+3<n
    int s = v.x + v.y + v.z + v.w;
    #pragma unroll
    for (int off = 32; off; off >>= 1) s += __shfl_down(s, off, 64);
    __shared__ int ws[4];
    if ((t & 63) == 0) ws[t >> 6] = s;
    __syncthreads();
    if (t == 0) bsum[blockIdx.x] = ws[0] + ws[1] + ws[2] + ws[3];
}

// pass 2: exclusive scan of the 98 block sums (one small block).
__global__ void k_scan2(const int* __restrict__ bsum, int* __restrict__ boff, int nb) {
    __shared__ int buf[128];
    int t = threadIdx.x;
    int v = (t < nb) ? bsum[t] : 0;
    buf[t] = v;
    __syncthreads();
    for (int off = 1; off < 128; off <<= 1) {
        int u = (t >= off) ? buf[t - off] : 0;
        __syncthreads();
        buf[t] += u;
        __syncthreads();
    }
    if (t < nb) boff[t] = buf[t] - v;  // exclusive
}

// pass 3: local scan + block offset -> row_ptr (exclusive prefix of cnt).
__global__ void k_scan3(const int* __restrict__ cnt, const int* __restrict__ boff,
                        int* __restrict__ row_ptr, int n) {
    int t = threadIdx.x;
    int base = blockIdx.x * 1024 + t * 4;
    int4 v = {0, 0, 0, 0};
    if (base < n) v = *(const int4*)(cnt + base);
    int s = v.x + v.y + v.z + v.w;
    int lane = t & 63;
    int ps = s;  // inclusive wave scan
    #pragma unroll
    for (int off = 1; off < 64; off <<= 1) {
        int u = __shfl_up(ps, off, 64);
        if (lane >= off) ps += u;
    }
    __shared__ int ws[4];
    if (lane == 63) ws[t >> 6] = ps;
    __syncthreads();
    int w = t >> 6;
    int woff = 0;
    for (int i = 0; i < 4; ++i) woff += (i < w) ? ws[i] : 0;
    int excl = boff[blockIdx.x] + woff + ps - s;
    if (base < n) {
        row_ptr[base] = excl;          excl += v.x;
        row_ptr[base + 1] = excl;      excl += v.y;
        row_ptr[base + 2] = excl;      excl += v.z;
        row_ptr[base + 3] = excl;
    }
    if (blockIdx.x == 0 && t == 0) row_ptr[n] = NE;  // total edges is constant
}

__global__ void k_dinv(const int* __restrict__ cnt, float* __restrict__ dinv, int n) {
    int i = blockIdx.x * blockDim.x + threadIdx.x;
    if (i < n) dinv[i] = rsqrtf((float)(cnt[i] + 1));  // self-loop counted
}

__global__ void k_fill(const int* __restrict__ src, const int* __restrict__ dst,
                       const int* __restrict__ row_ptr, int* __restrict__ fill,
                       int* __restrict__ csr_src, int E) {
    int i = blockIdx.x * blockDim.x + threadIdx.x;
    if (i < E) {
        int d = dst[i];
        int pos = row_ptr[d] + atomicAdd(&fill[d], 1);
        csr_src[pos] = src[i];
    }
}

// ---------------- dense matmuls (output pre-scaled by dinv[node]) ----------------

__global__ void k_mm1(const float* __restrict__ x, const float* __restrict__ W,
                      const float* __restrict__ dinv, float* __restrict__ out, int n) {
    __shared__ float Ws[9 * 64];
    int tid = threadIdx.x;
    for (int i = tid; i < 9 * 64; i += 256) Ws[i] = W[i];
    __syncthreads();
    int node = blockIdx.x * 4 + (tid >> 6);
    int f = tid & 63;
    if (node < n) {
        float acc = 0.f;
        #pragma unroll
        for (int k = 0; k < 9; ++k) acc += x[node * 9 + k] * Ws[k * 64 + f];
        out[node * 64 + f] = acc * dinv[node];
    }
}

// 16 nodes / block, 4 nodes / wave, lane = output feature.
__global__ void k_mm64(const float* __restrict__ h, const float* __restrict__ W,
                       const float* __restrict__ dinv, float* __restrict__ out, int n) {
    __shared__ float Wt[64][68];   // W^T, stride 68: keeps float4 16B-aligned, banks spread
    __shared__ float xs[16][64];
    int tid = threadIdx.x;
    for (int i = tid; i < 4096; i += 256) Wt[i & 63][i >> 6] = W[i];
    int nb = blockIdx.x * 16;
    {
        float4 v = {0, 0, 0, 0};
        int nfloat = (min(16, n - nb)) * 64;
        if (tid * 4 < nfloat) v = ((const float4*)(h + (size_t)nb * 64))[tid];
        ((float4*)&xs[0][0])[tid] = v;
    }
    __syncthreads();
    int w = tid >> 6, f = tid & 63;
    int n0 = nb + w * 4;
    float acc0 = 0.f, acc1 = 0.f, acc2 = 0.f, acc3 = 0.f;
    #pragma unroll
    for (int k = 0; k < 64; k += 4) {
        float4 wt = *(const float4*)&Wt[f][k];
        float4 x0 = *(const float4*)&xs[w * 4 + 0][k];
        float4 x1 = *(const float4*)&xs[w * 4 + 1][k];
        float4 x2 = *(const float4*)&xs[w * 4 + 2][k];
        float4 x3 = *(const float4*)&xs[w * 4 + 3][k];
        acc0 += wt.x * x0.x + wt.y * x0.y + wt.z * x0.z + wt.w * x0.w;
        acc1 += wt.x * x1.x + wt.y * x1.y + wt.z * x1.z + wt.w * x1.w;
        acc2 += wt.x * x2.x + wt.y * x2.y + wt.z * x2.z + wt.w * x2.w;
        acc3 += wt.x * x3.x + wt.y * x3.y + wt.z * x3.z + wt.w * x3.w;
    }
    if (n0 + 0 < n) out[(size_t)(n0 + 0) * 64 + f] = acc0 * dinv[n0 + 0];
    if (n0 + 1 < n) out[(size_t)(n0 + 1) * 64 + f] = acc1 * dinv[n0 + 1];
    if (n0 + 2 < n) out[(size_t)(n0 + 2) * 64 + f] = acc2 * dinv[n0 + 2];
    if (n0 + 3 < n) out[(size_t)(n0 + 3) * 64 + f] = acc3 * dinv[n0 + 3];
}

// ---------------- CSR aggregation (+ self loop + bias + relu) ----------------
// hs is pre-scaled by dinv[node]; result = (hs[dst] + sum hs[src]) * dinv[dst].

__global__ void k_agg(const float* __restrict__ hs, float* __restrict__ hout,
                      const int* __restrict__ csr_src, const int* __restrict__ row_ptr,
                      const float* __restrict__ dinv, const float* __restrict__ bias, int n) {
    int tid = threadIdx.x;
    int node = blockIdx.x * 4 + (tid >> 6);
    int f = tid & 63;
    if (node >= n) return;
    int beg = row_ptr[node], endp = row_ptr[node + 1];
    float acc = hs[(size_t)node * 64 + f];
    for (int e = beg; e < endp; ++e) {
        int s = csr_src[e];
        acc += hs[(size_t)s * 64 + f];
    }
    float v = acc * dinv[node] + bias[f];
    hout[(size_t)node * 64 + f] = fmaxf(v, 0.f);
}

// ---------------- pooling ----------------

__global__ void k_count(const int* __restrict__ batch, int* __restrict__ pcnt, int n) {
    int i = blockIdx.x * blockDim.x + threadIdx.x;
    if (i < n) atomicAdd(&pcnt[batch[i]], 1);
}

// batch is sorted: wave accumulates 16 consecutive nodes in registers,
// flushes atomics only at graph boundaries.
__global__ void k_pool(const float* __restrict__ h, const int* __restrict__ batch,
                       float* __restrict__ psum, float* __restrict__ pmax, int n) {
    int lane = threadIdx.x & 63;
    int w = threadIdx.x >> 6;
    int n0 = blockIdx.x * 64 + w * 16;
    if (n0 >= n) return;
    int n1 = min(n0 + 16, n);
    int curg = batch[n0];
    float sum = 0.f, mx = 0.f;
    for (int node = n0; node < n1; ++node) {
        int g = batch[node];
        if (g != curg) {
            atomicAdd(&psum[curg * 64 + lane], sum);
            atomicMax((int*)&pmax[curg * 64 + lane], __float_as_int(mx));
            sum = 0.f; mx = 0.f; curg = g;
        }
        float v = h[(size_t)node * 64 + lane];
        sum += v;
        mx = fmaxf(mx, v);
    }
    atomicAdd(&psum[curg * 64 + lane], sum);
    atomicMax((int*)&pmax[curg * 64 + lane], __float_as_int(mx));  // h >= 0 after relu
}

// ---------------- predictor MLP ----------------

__global__ void k_pred(const float* __restrict__ psum, const float* __restrict__ pmax,
                       const int* __restrict__ pcnt,
                       const float* __restrict__ Wp1, const float* __restrict__ bp1,
                       const float* __restrict__ Wp2, const float* __restrict__ bp2,
                       float* __restrict__ out, int G) {
    __shared__ float gs[4][128];
    int tid = threadIdx.x;
    int li = tid >> 6;
    int lane = tid & 63;
    int gi = blockIdx.x * 4 + li;
    if (gi < G) {
        float c = fmaxf((float)pcnt[gi], 1.0f);
        gs[li][lane] = psum[gi * 64 + lane] / c;
        gs[li][64 + lane] = pmax[gi * 64 + lane];
    }
    __syncthreads();
    if (gi >= G) return;
    float acc = bp1[lane];
    #pragma unroll
    for (int k = 0; k < 128; ++k) acc += gs[li][k] * Wp1[k * 64 + lane];
    acc = fmaxf(acc, 0.f);
    float r = acc * Wp2[lane];
    #pragma unroll
    for (int off = 32; off; off >>= 1) r += __shfl_down(r, off, 64);
    if (lane == 0) out[gi] = r + bp2[0];
}

// ---------------- launch ----------------

extern "C" void kernel_launch(void* const* d_in, const int* in_sizes, int n_in,
                              void* d_out, int out_size, void* d_ws, size_t ws_size,
                              hipStream_t stream) {
    const float* x    = (const float*)d_in[0];
    const int*   esrc = (const int*)d_in[1];
    const int*   edst = (const int*)d_in[2];
    const int*   batch= (const int*)d_in[3];
    const float* W1 = (const float*)d_in[4];  const float* b1 = (const float*)d_in[5];
    const float* W2 = (const float*)d_in[6];  const float* b2 = (const float*)d_in[7];
    const float* W3 = (const float*)d_in[8];  const float* b3 = (const float*)d_in[9];
    const float* Wp1= (const float*)d_in[10]; const float* bp1= (const float*)d_in[11];
    const float* Wp2= (const float*)d_in[12]; const float* bp2= (const float*)d_in[13];
    float* out = (float*)d_out;

    char* ws = (char*)d_ws;
    // zero-init region (contiguous): [cnt][fill][psum][pmax][pcnt]
    int*   cnt     = (int*)  (ws + 0);          // N ints
    int*   fill    = (int*)  (ws + 400000);     // N ints
    float* psum    = (float*)(ws + 800000);     // G*64 floats
    float* pmax    = (float*)(ws + 1324288);    // G*64 floats
    int*   pcnt    = (int*)  (ws + 1848576);    // G ints
    const size_t ZBYTES = 1856768;
    float* dinv    = (float*)(ws + 1856768);    // N floats
    int*   row_ptr = (int*)  (ws + 2256768);    // N+1 ints (padded to 400128)
    int*   bsum    = (int*)  (ws + 2656896);    // 128 ints
    int*   boff    = (int*)  (ws + 2657408);    // 128 ints
    int*   csr_src = (int*)  (ws + 2657920);    // E ints
    float* hA      = (float*)(ws + 6657920);    // N*64 floats
    float* hB      = (float*)(ws + 32257920);   // N*64 floats

    hipMemsetAsync(ws, 0, ZBYTES, stream);

    k_deg  <<<(NE + 255) / 256, 256, 0, stream>>>(edst, cnt, NE);
    k_scan1<<<NBLK, 256, 0, stream>>>(cnt, bsum, NN);
    k_scan2<<<1, 128, 0, stream>>>(bsum, boff, NBLK);
    k_scan3<<<NBLK, 256, 0, stream>>>(cnt, boff, row_ptr, NN);
    k_dinv <<<(NN + 255) / 256, 256, 0, stream>>>(cnt, dinv, NN);
    k_fill <<<(NE + 255) / 256, 256, 0, stream>>>(esrc, edst, row_ptr, fill, csr_src, NE);

    int nb4 = (NN + 3) / 4;
    int nb16 = (NN + 15) / 16;
    k_mm1 <<<nb4, 256, 0, stream>>>(x, W1, dinv, hA, NN);
    k_agg <<<nb4, 256, 0, stream>>>(hA, hB, csr_src, row_ptr, dinv, b1, NN);
    k_mm64<<<nb16, 256, 0, stream>>>(hB, W2, dinv, hA, NN);
    k_agg <<<nb4, 256, 0, stream>>>(hA, hB, csr_src, row_ptr, dinv, b2, NN);
    k_mm64<<<nb16, 256, 0, stream>>>(hB, W3, dinv, hA, NN);
    k_agg <<<nb4, 256, 0, stream>>>(hA, hB, csr_src, row_ptr, dinv, b3, NN);

    k_count<<<(NN + 255) / 256, 256, 0, stream>>>(batch, pcnt, NN);
    k_pool <<<(NN + 63) / 64, 256, 0, stream>>>(hB, batch, psum, pmax, NN);
    k_pred <<<(NG + 3) / 4, 256, 0, stream>>>(psum, pmax, pcnt, Wp1, bp1, Wp2, bp2, out, NG);
}

// Round 3
// 380.143 us; speedup vs baseline: 2.6242x; 2.6242x over previous
//
#include <hip/hip_runtime.h>

#define NN 100000
#define NE 1000000
#define NG 2048
#define NBLK 98  // ceil(NN/1024)

__device__ __forceinline__ float rl(float v, int k) {
    return __int_as_float(__builtin_amdgcn_readlane(__float_as_int(v), k));
}

// ---------------- graph preprocessing ----------------

__global__ void k_deg(const int* __restrict__ dst, int* __restrict__ cnt, int E) {
    int i = blockIdx.x * blockDim.x + threadIdx.x;
    if (i < E) atomicAdd(&cnt[dst[i]], 1);
}

__global__ void k_scan1(const int* __restrict__ cnt, int* __restrict__ bsum, int n) {
    int t = threadIdx.x;
    int base = blockIdx.x * 1024 + t * 4;
    int4 v = {0, 0, 0, 0};
    if (base < n) v = *(const int4*)(cnt + base);  // n % 4 == 0
    int s = v.x + v.y + v.z + v.w;
    #pragma unroll
    for (int off = 32; off; off >>= 1) s += __shfl_down(s, off, 64);
    __shared__ int ws[4];
    if ((t & 63) == 0) ws[t >> 6] = s;
    __syncthreads();
    if (t == 0) bsum[blockIdx.x] = ws[0] + ws[1] + ws[2] + ws[3];
}

__global__ void k_scan2(const int* __restrict__ bsum, int* __restrict__ boff, int nb) {
    __shared__ int buf[128];
    int t = threadIdx.x;
    int v = (t < nb) ? bsum[t] : 0;
    buf[t] = v;
    __syncthreads();
    for (int off = 1; off < 128; off <<= 1) {
        int u = (t >= off) ? buf[t - off] : 0;
        __syncthreads();
        buf[t] += u;
        __syncthreads();
    }
    if (t < nb) boff[t] = buf[t] - v;  // exclusive
}

__global__ void k_scan3(const int* __restrict__ cnt, const int* __restrict__ boff,
                        int* __restrict__ row_ptr, int n) {
    int t = threadIdx.x;
    int base = blockIdx.x * 1024 + t * 4;
    int4 v = {0, 0, 0, 0};
    if (base < n) v = *(const int4*)(cnt + base);
    int s = v.x + v.y + v.z + v.w;
    int lane = t & 63;
    int ps = s;
    #pragma unroll
    for (int off = 1; off < 64; off <<= 1) {
        int u = __shfl_up(ps, off, 64);
        if (lane >= off) ps += u;
    }
    __shared__ int ws[4];
    if (lane == 63) ws[t >> 6] = ps;
    __syncthreads();
    int w = t >> 6;
    int woff = 0;
    for (int i = 0; i < 4; ++i) woff += (i < w) ? ws[i] : 0;
    int excl = boff[blockIdx.x] + woff + ps - s;
    if (base < n) {
        row_ptr[base] = excl;          excl += v.x;
        row_ptr[base + 1] = excl;      excl += v.y;
        row_ptr[base + 2] = excl;      excl += v.z;
        row_ptr[base + 3] = excl;
    }
    if (blockIdx.x == 0 && t == 0) row_ptr[n] = NE;
}

__global__ void k_dinv(const int* __restrict__ cnt, float* __restrict__ dinv, int n) {
    int i = blockIdx.x * blockDim.x + threadIdx.x;
    if (i < n) dinv[i] = rsqrtf((float)(cnt[i] + 1));
}

__global__ void k_fill(const int* __restrict__ src, const int* __restrict__ dst,
                       const int* __restrict__ row_ptr, int* __restrict__ fill,
                       int* __restrict__ csr_src, int E) {
    int i = blockIdx.x * blockDim.x + threadIdx.x;
    if (i < E) {
        int d = dst[i];
        int pos = row_ptr[d] + atomicAdd(&fill[d], 1);
        csr_src[pos] = src[i];
    }
}

__global__ void k_count(const int* __restrict__ batch, int* __restrict__ pcnt, int n) {
    int i = blockIdx.x * blockDim.x + threadIdx.x;
    if (i < n) atomicAdd(&pcnt[batch[i]], 1);
}

// ---------------- fused GCN layer ----------------
// Identity: relu(Agg(a.W)+b) == relu((dinv .* (p_self + sum_src p_src)) . W + b)
// with p = a .* dinv (exact algebra; Agg and W commute since both are linear).
// KD=9: input is raw x, scale by dinv[src] inline. KD=64: input is pre-scaled p.
// POOL=1 (layer 3): fuse mean/max pooling, no activation store.
// Wave = 8 consecutive nodes, lane = output feature. Matvec via v_readlane:
// one conflict-free Ws read per k serves 8 nodes' FMAs.

template <int KD, int POOL>
__global__ __launch_bounds__(256, 4)
void k_layer(const float* __restrict__ pin, const float* __restrict__ W,
             const float* __restrict__ bias, const float* __restrict__ dinv,
             const int* __restrict__ csr, const int* __restrict__ rp,
             const int* __restrict__ batch,
             float* __restrict__ pout, float* __restrict__ psum,
             float* __restrict__ pmax) {
    __shared__ float Ws[KD * 64];
    int tid = threadIdx.x;
    for (int i = tid; i < KD * 64; i += 256) Ws[i] = W[i];
    __syncthreads();
    int f = tid & 63;
    int wv = tid >> 6;
    int n0 = (blockIdx.x * 4 + wv) * 8;           // NN == 3125*32: no tail
    int fi = (KD < 64) ? ((f < KD) ? f : (KD - 1)) : f;

    float q0, q1, q2, q3, q4, q5, q6, q7;
#define GATHER(Q, J) { \
    int nd = n0 + (J); \
    int beg = rp[nd], endp = rp[nd + 1]; \
    float acc = pin[nd * KD + fi]; \
    if (KD == 9) acc *= dinv[nd]; \
    int e = beg; \
    for (; e + 3 < endp; e += 4) { \
        int s0 = csr[e], s1 = csr[e + 1], s2 = csr[e + 2], s3 = csr[e + 3]; \
        float a0 = pin[s0 * KD + fi], a1 = pin[s1 * KD + fi]; \
        float a2 = pin[s2 * KD + fi], a3 = pin[s3 * KD + fi]; \
        if (KD == 9) { a0 *= dinv[s0]; a1 *= dinv[s1]; a2 *= dinv[s2]; a3 *= dinv[s3]; } \
        acc += (a0 + a1) + (a2 + a3); \
    } \
    for (; e < endp; ++e) { \
        int s = csr[e]; \
        float a = pin[s * KD + fi]; \
        if (KD == 9) a *= dinv[s]; \
        acc += a; \
    } \
    Q = acc * dinv[nd]; \
}
    GATHER(q0, 0) GATHER(q1, 1) GATHER(q2, 2) GATHER(q3, 3)
    GATHER(q4, 4) GATHER(q5, 5) GATHER(q6, 6) GATHER(q7, 7)
#undef GATHER

    float bv = bias[f];
    float o0 = bv, o1 = bv, o2 = bv, o3 = bv, o4 = bv, o5 = bv, o6 = bv, o7 = bv;
    #pragma unroll
    for (int k = 0; k < KD; ++k) {
        float wsv = Ws[k * 64 + f];               // lane=f -> bank f%32: conflict-free
        o0 = fmaf(rl(q0, k), wsv, o0);
        o1 = fmaf(rl(q1, k), wsv, o1);
        o2 = fmaf(rl(q2, k), wsv, o2);
        o3 = fmaf(rl(q3, k), wsv, o3);
        o4 = fmaf(rl(q4, k), wsv, o4);
        o5 = fmaf(rl(q5, k), wsv, o5);
        o6 = fmaf(rl(q6, k), wsv, o6);
        o7 = fmaf(rl(q7, k), wsv, o7);
    }

    if (POOL == 0) {
#define STORE(O, J) pout[(n0 + (J)) * 64 + f] = fmaxf(O, 0.f) * dinv[n0 + (J)];
        STORE(o0, 0) STORE(o1, 1) STORE(o2, 2) STORE(o3, 3)
        STORE(o4, 4) STORE(o5, 5) STORE(o6, 6) STORE(o7, 7)
#undef STORE
    } else {
        int g = batch[n0];
        float sum = 0.f, mx = 0.f;
#define ACCP(O, J) { \
    float r = fmaxf(O, 0.f); \
    int gj = batch[n0 + (J)]; \
    if (gj != g) { \
        atomicAdd(&psum[g * 64 + f], sum); \
        atomicMax((int*)&pmax[g * 64 + f], __float_as_int(mx)); \
        g = gj; sum = 0.f; mx = 0.f; \
    } \
    sum += r; mx = fmaxf(mx, r); \
}
        ACCP(o0, 0) ACCP(o1, 1) ACCP(o2, 2) ACCP(o3, 3)
        ACCP(o4, 4) ACCP(o5, 5) ACCP(o6, 6) ACCP(o7, 7)
#undef ACCP
        atomicAdd(&psum[g * 64 + f], sum);
        atomicMax((int*)&pmax[g * 64 + f], __float_as_int(mx));  // relu => mx >= 0
    }
}

// ---------------- predictor MLP ----------------

__global__ void k_pred(const float* __restrict__ psum, const float* __restrict__ pmax,
                       const int* __restrict__ pcnt,
                       const float* __restrict__ Wp1, const float* __restrict__ bp1,
                       const float* __restrict__ Wp2, const float* __restrict__ bp2,
                       float* __restrict__ out, int G) {
    __shared__ float gs[4][128];
    int tid = threadIdx.x;
    int li = tid >> 6;
    int lane = tid & 63;
    int gi = blockIdx.x * 4 + li;
    if (gi < G) {
        float c = fmaxf((float)pcnt[gi], 1.0f);
        gs[li][lane] = psum[gi * 64 + lane] / c;
        gs[li][64 + lane] = pmax[gi * 64 + lane];
    }
    __syncthreads();
    if (gi >= G) return;
    float acc = bp1[lane];
    #pragma unroll
    for (int k = 0; k < 128; ++k) acc += gs[li][k] * Wp1[k * 64 + lane];
    acc = fmaxf(acc, 0.f);
    float r = acc * Wp2[lane];
    #pragma unroll
    for (int off = 32; off; off >>= 1) r += __shfl_down(r, off, 64);
    if (lane == 0) out[gi] = r + bp2[0];
}

// ---------------- launch ----------------

extern "C" void kernel_launch(void* const* d_in, const int* in_sizes, int n_in,
                              void* d_out, int out_size, void* d_ws, size_t ws_size,
                              hipStream_t stream) {
    const float* x    = (const float*)d_in[0];
    const int*   esrc = (const int*)d_in[1];
    const int*   edst = (const int*)d_in[2];
    const int*   batch= (const int*)d_in[3];
    const float* W1 = (const float*)d_in[4];  const float* b1 = (const float*)d_in[5];
    const float* W2 = (const float*)d_in[6];  const float* b2 = (const float*)d_in[7];
    const float* W3 = (const float*)d_in[8];  const float* b3 = (const float*)d_in[9];
    const float* Wp1= (const float*)d_in[10]; const float* bp1= (const float*)d_in[11];
    const float* Wp2= (const float*)d_in[12]; const float* bp2= (const float*)d_in[13];
    float* out = (float*)d_out;

    char* ws = (char*)d_ws;
    // zero-init region (contiguous): [cnt][fill][psum][pmax][pcnt]
    int*   cnt     = (int*)  (ws + 0);          // N ints
    int*   fill    = (int*)  (ws + 400000);     // N ints
    float* psum    = (float*)(ws + 800000);     // G*64 floats
    float* pmax    = (float*)(ws + 1324288);    // G*64 floats
    int*   pcnt    = (int*)  (ws + 1848576);    // G ints
    const size_t ZBYTES = 1856768;
    float* dinv    = (float*)(ws + 1856768);    // N floats
    int*   row_ptr = (int*)  (ws + 2256768);    // N+1 ints (padded)
    int*   bsum    = (int*)  (ws + 2656896);    // 128 ints
    int*   boff    = (int*)  (ws + 2657408);    // 128 ints
    int*   csr_src = (int*)  (ws + 2657920);    // E ints
    float* p1      = (float*)(ws + 6657920);    // N*64 floats
    float* p2      = (float*)(ws + 32257920);   // N*64 floats (ends 57857920)

    hipMemsetAsync(ws, 0, ZBYTES, stream);

    k_deg  <<<(NE + 255) / 256, 256, 0, stream>>>(edst, cnt, NE);
    k_scan1<<<NBLK, 256, 0, stream>>>(cnt, bsum, NN);
    k_scan2<<<1, 128, 0, stream>>>(bsum, boff, NBLK);
    k_scan3<<<NBLK, 256, 0, stream>>>(cnt, boff, row_ptr, NN);
    k_dinv <<<(NN + 255) / 256, 256, 0, stream>>>(cnt, dinv, NN);
    k_fill <<<(NE + 255) / 256, 256, 0, stream>>>(esrc, edst, row_ptr, fill, csr_src, NE);
    k_count<<<(NN + 255) / 256, 256, 0, stream>>>(batch, pcnt, NN);

    int nbl = NN / 32;  // 3125, exact
    k_layer<9, 0><<<nbl, 256, 0, stream>>>(x,  W1, b1, dinv, csr_src, row_ptr, batch, p1, psum, pmax);
    k_layer<64, 0><<<nbl, 256, 0, stream>>>(p1, W2, b2, dinv, csr_src, row_ptr, batch, p2, psum, pmax);
    k_layer<64, 1><<<nbl, 256, 0, stream>>>(p2, W3, b3, dinv, csr_src, row_ptr, batch, p1, psum, pmax);

    k_pred <<<(NG + 3) / 4, 256, 0, stream>>>(psum, pmax, pcnt, Wp1, bp1, Wp2, bp2, out, NG);
}

// Round 4
// 327.166 us; speedup vs baseline: 3.0491x; 1.1619x over previous
//
#include <hip/hip_runtime.h>

#define NN 100000
#define NE 1000000
#define NG 2048
#define NBLK 98   // ceil(NN/1024)
#define SPEC 16   // speculative edges per node (covers ~98% of Poisson(10) degrees)

__device__ __forceinline__ float rl(float v, int k) {
    return __int_as_float(__builtin_amdgcn_readlane(__float_as_int(v), k));
}
__device__ __forceinline__ int rli(int v, int k) {
    return __builtin_amdgcn_readlane(v, k);
}

// ---------------- graph preprocessing ----------------

// fused: degree count (edges) + per-graph node count
__global__ void k_cnt(const int* __restrict__ dst, int* __restrict__ cnt,
                      const int* __restrict__ batch, int* __restrict__ pcnt) {
    int i = blockIdx.x * blockDim.x + threadIdx.x;
    if (i < NE) atomicAdd(&cnt[dst[i]], 1);
    if (i < NN) atomicAdd(&pcnt[batch[i]], 1);
}

__global__ void k_scan1(const int* __restrict__ cnt, int* __restrict__ bsum, int n) {
    int t = threadIdx.x;
    int base = blockIdx.x * 1024 + t * 4;
    int4 v = {0, 0, 0, 0};
    if (base < n) v = *(const int4*)(cnt + base);  // n % 4 == 0
    int s = v.x + v.y + v.z + v.w;
    #pragma unroll
    for (int off = 32; off; off >>= 1) s += __shfl_down(s, off, 64);
    __shared__ int ws[4];
    if ((t & 63) == 0) ws[t >> 6] = s;
    __syncthreads();
    if (t == 0) bsum[blockIdx.x] = ws[0] + ws[1] + ws[2] + ws[3];
}

__global__ void k_scan2(const int* __restrict__ bsum, int* __restrict__ boff, int nb) {
    __shared__ int buf[128];
    int t = threadIdx.x;
    int v = (t < nb) ? bsum[t] : 0;
    buf[t] = v;
    __syncthreads();
    for (int off = 1; off < 128; off <<= 1) {
        int u = (t >= off) ? buf[t - off] : 0;
        __syncthreads();
        buf[t] += u;
        __syncthreads();
    }
    if (t < nb) boff[t] = buf[t] - v;  // exclusive
}

__global__ void k_scan3(const int* __restrict__ cnt, const int* __restrict__ boff,
                        int* __restrict__ row_ptr, int n) {
    int t = threadIdx.x;
    int base = blockIdx.x * 1024 + t * 4;
    int4 v = {0, 0, 0, 0};
    if (base < n) v = *(const int4*)(cnt + base);
    int s = v.x + v.y + v.z + v.w;
    int lane = t & 63;
    int ps = s;
    #pragma unroll
    for (int off = 1; off < 64; off <<= 1) {
        int u = __shfl_up(ps, off, 64);
        if (lane >= off) ps += u;
    }
    __shared__ int ws[4];
    if (lane == 63) ws[t >> 6] = ps;
    __syncthreads();
    int w = t >> 6;
    int woff = 0;
    for (int i = 0; i < 4; ++i) woff += (i < w) ? ws[i] : 0;
    int excl = boff[blockIdx.x] + woff + ps - s;
    if (base < n) {
        row_ptr[base] = excl;          excl += v.x;
        row_ptr[base + 1] = excl;      excl += v.y;
        row_ptr[base + 2] = excl;      excl += v.z;
        row_ptr[base + 3] = excl;
    }
    if (blockIdx.x == 0 && t == 0) row_ptr[n] = NE;
}

__global__ void k_dinv(const int* __restrict__ cnt, float* __restrict__ dinv, int n) {
    int i = blockIdx.x * blockDim.x + threadIdx.x;
    if (i < n) dinv[i] = rsqrtf((float)(cnt[i] + 1));
}

__global__ void k_fill(const int* __restrict__ src, const int* __restrict__ dst,
                       const int* __restrict__ row_ptr, int* __restrict__ fill,
                       int* __restrict__ csr_src, int E) {
    int i = blockIdx.x * blockDim.x + threadIdx.x;
    if (i < E) {
        int d = dst[i];
        int pos = row_ptr[d] + atomicAdd(&fill[d], 1);
        csr_src[pos] = src[i];
    }
}

// ---------------- fused GCN layer ----------------
// relu(Agg(a.W)+b) == relu((dinv .* (p_self + sum_src p_src)) . W + b),  p = a .* dinv.
// KD=9: pin is raw x, scale each gathered row by dinv[src] (src is SGPR -> scalar load).
// KD=64: pin is pre-scaled p. POOL=1: fuse mean/max pooling (batch sorted).
// Gather: lane-parallel CSR read (one coalesced load = whole adjacency),
// readfirstlane-uniform bounds, v_readlane source ids -> SGPR-base feature loads,
// SPEC independent loads in flight, masked tree-sum; uniform tail loop for deg>SPEC.

template <int KD, int POOL>
__global__ __launch_bounds__(256, 4)
void k_layer(const float* __restrict__ pin, const float* __restrict__ W,
             const float* __restrict__ bias, const float* __restrict__ dinv,
             const int* __restrict__ csr, const int* __restrict__ rp,
             const int* __restrict__ batch,
             float* __restrict__ pout, float* __restrict__ psum,
             float* __restrict__ pmax) {
    __shared__ float Ws[KD * 64];
    int tid = threadIdx.x;
    for (int i = tid; i < KD * 64; i += 256) Ws[i] = W[i];
    __syncthreads();
    int f = tid & 63;
    int lane = f;
    int wv = tid >> 6;
    int n0 = (blockIdx.x * 4 + wv) * 8;           // NN == 3125*32: no tail
    int fi = (KD < 64) ? ((f < KD) ? f : (KD - 1)) : f;

    float q0, q1, q2, q3, q4, q5, q6, q7;
#define GATHER(Q, J) { \
    int nd = n0 + (J); \
    int beg = __builtin_amdgcn_readfirstlane(rp[nd]); \
    int deg = __builtin_amdgcn_readfirstlane(rp[nd + 1]) - beg; \
    int lidx = beg + min(lane, max(deg - 1, 0)); \
    int myE = csr[min(lidx, NE - 1)]; \
    float acc = pin[(size_t)nd * KD + fi]; \
    if (KD == 9) acc *= dinv[nd]; \
    float t[SPEC]; \
    _Pragma("unroll") \
    for (int k = 0; k < SPEC; ++k) { \
        int s = rli(myE, k); \
        s = min(max(s, 0), NN - 1); \
        float a = pin[(size_t)s * KD + fi]; \
        if (KD == 9) a *= dinv[s]; \
        t[k] = a; \
    } \
    float p0 = 0.f, p1v = 0.f, p2v = 0.f, p3v = 0.f; \
    _Pragma("unroll") \
    for (int k = 0; k < SPEC; k += 4) { \
        p0 += (k + 0 < deg) ? t[k + 0] : 0.f; \
        p1v += (k + 1 < deg) ? t[k + 1] : 0.f; \
        p2v += (k + 2 < deg) ? t[k + 2] : 0.f; \
        p3v += (k + 3 < deg) ? t[k + 3] : 0.f; \
    } \
    acc += (p0 + p1v) + (p2v + p3v); \
    for (int k = SPEC; k < deg; ++k) { \
        int s = __builtin_amdgcn_readfirstlane(csr[beg + k]); \
        float a = pin[(size_t)s * KD + fi]; \
        if (KD == 9) a *= dinv[s]; \
        acc += a; \
    } \
    Q = acc * dinv[nd]; \
}
    GATHER(q0, 0) GATHER(q1, 1) GATHER(q2, 2) GATHER(q3, 3)
    GATHER(q4, 4) GATHER(q5, 5) GATHER(q6, 6) GATHER(q7, 7)
#undef GATHER

    float bv = bias[f];
    float o0 = bv, o1 = bv, o2 = bv, o3 = bv, o4 = bv, o5 = bv, o6 = bv, o7 = bv;
    #pragma unroll
    for (int k = 0; k < KD; ++k) {
        float wsv = Ws[k * 64 + f];               // lane=f -> bank f%32: conflict-free
        o0 = fmaf(rl(q0, k), wsv, o0);
        o1 = fmaf(rl(q1, k), wsv, o1);
        o2 = fmaf(rl(q2, k), wsv, o2);
        o3 = fmaf(rl(q3, k), wsv, o3);
        o4 = fmaf(rl(q4, k), wsv, o4);
        o5 = fmaf(rl(q5, k), wsv, o5);
        o6 = fmaf(rl(q6, k), wsv, o6);
        o7 = fmaf(rl(q7, k), wsv, o7);
    }

    if (POOL == 0) {
#define STORE(O, J) pout[(size_t)(n0 + (J)) * 64 + f] = fmaxf(O, 0.f) * dinv[n0 + (J)];
        STORE(o0, 0) STORE(o1, 1) STORE(o2, 2) STORE(o3, 3)
        STORE(o4, 4) STORE(o5, 5) STORE(o6, 6) STORE(o7, 7)
#undef STORE
    } else {
        int g = batch[n0];
        float sum = 0.f, mx = 0.f;
#define ACCP(O, J) { \
    float r = fmaxf(O, 0.f); \
    int gj = batch[n0 + (J)]; \
    if (gj != g) { \
        atomicAdd(&psum[g * 64 + f], sum); \
        atomicMax((int*)&pmax[g * 64 + f], __float_as_int(mx)); \
        g = gj; sum = 0.f; mx = 0.f; \
    } \
    sum += r; mx = fmaxf(mx, r); \
}
        ACCP(o0, 0) ACCP(o1, 1) ACCP(o2, 2) ACCP(o3, 3)
        ACCP(o4, 4) ACCP(o5, 5) ACCP(o6, 6) ACCP(o7, 7)
#undef ACCP
        atomicAdd(&psum[g * 64 + f], sum);
        atomicMax((int*)&pmax[g * 64 + f], __float_as_int(mx));  // relu => mx >= 0
    }
}

// ---------------- predictor MLP ----------------

__global__ void k_pred(const float* __restrict__ psum, const float* __restrict__ pmax,
                       const int* __restrict__ pcnt,
                       const float* __restrict__ Wp1, const float* __restrict__ bp1,
                       const float* __restrict__ Wp2, const float* __restrict__ bp2,
                       float* __restrict__ out, int G) {
    __shared__ float gs[4][128];
    int tid = threadIdx.x;
    int li = tid >> 6;
    int lane = tid & 63;
    int gi = blockIdx.x * 4 + li;
    if (gi < G) {
        float c = fmaxf((float)pcnt[gi], 1.0f);
        gs[li][lane] = psum[gi * 64 + lane] / c;
        gs[li][64 + lane] = pmax[gi * 64 + lane];
    }
    __syncthreads();
    if (gi >= G) return;
    float acc = bp1[lane];
    #pragma unroll
    for (int k = 0; k < 128; ++k) acc += gs[li][k] * Wp1[k * 64 + lane];
    acc = fmaxf(acc, 0.f);
    float r = acc * Wp2[lane];
    #pragma unroll
    for (int off = 32; off; off >>= 1) r += __shfl_down(r, off, 64);
    if (lane == 0) out[gi] = r + bp2[0];
}

// ---------------- launch ----------------

extern "C" void kernel_launch(void* const* d_in, const int* in_sizes, int n_in,
                              void* d_out, int out_size, void* d_ws, size_t ws_size,
                              hipStream_t stream) {
    const float* x    = (const float*)d_in[0];
    const int*   esrc = (const int*)d_in[1];
    const int*   edst = (const int*)d_in[2];
    const int*   batch= (const int*)d_in[3];
    const float* W1 = (const float*)d_in[4];  const float* b1 = (const float*)d_in[5];
    const float* W2 = (const float*)d_in[6];  const float* b2 = (const float*)d_in[7];
    const float* W3 = (const float*)d_in[8];  const float* b3 = (const float*)d_in[9];
    const float* Wp1= (const float*)d_in[10]; const float* bp1= (const float*)d_in[11];
    const float* Wp2= (const float*)d_in[12]; const float* bp2= (const float*)d_in[13];
    float* out = (float*)d_out;

    char* ws = (char*)d_ws;
    // zero-init region (contiguous): [cnt][fill][psum][pmax][pcnt]
    int*   cnt     = (int*)  (ws + 0);          // N ints
    int*   fill    = (int*)  (ws + 400000);     // N ints
    float* psum    = (float*)(ws + 800000);     // G*64 floats
    float* pmax    = (float*)(ws + 1324288);    // G*64 floats
    int*   pcnt    = (int*)  (ws + 1848576);    // G ints
    const size_t ZBYTES = 1856768;
    float* dinv    = (float*)(ws + 1856768);    // N floats
    int*   row_ptr = (int*)  (ws + 2256768);    // N+1 ints (padded)
    int*   bsum    = (int*)  (ws + 2656896);    // 128 ints
    int*   boff    = (int*)  (ws + 2657408);    // 128 ints
    int*   csr_src = (int*)  (ws + 2657920);    // E ints
    float* p1      = (float*)(ws + 6657920);    // N*64 floats
    float* p2      = (float*)(ws + 32257920);   // N*64 floats (ends 57857920)

    hipMemsetAsync(ws, 0, ZBYTES, stream);

    k_cnt  <<<(NE + 255) / 256, 256, 0, stream>>>(edst, cnt, batch, pcnt);
    k_scan1<<<NBLK, 256, 0, stream>>>(cnt, bsum, NN);
    k_scan2<<<1, 128, 0, stream>>>(bsum, boff, NBLK);
    k_scan3<<<NBLK, 256, 0, stream>>>(cnt, boff, row_ptr, NN);
    k_dinv <<<(NN + 255) / 256, 256, 0, stream>>>(cnt, dinv, NN);
    k_fill <<<(NE + 255) / 256, 256, 0, stream>>>(esrc, edst, row_ptr, fill, csr_src, NE);

    int nbl = NN / 32;  // 3125, exact
    k_layer<9, 0><<<nbl, 256, 0, stream>>>(x,  W1, b1, dinv, csr_src, row_ptr, batch, p1, psum, pmax);
    k_layer<64, 0><<<nbl, 256, 0, stream>>>(p1, W2, b2, dinv, csr_src, row_ptr, batch, p2, psum, pmax);
    k_layer<64, 1><<<nbl, 256, 0, stream>>>(p2, W3, b3, dinv, csr_src, row_ptr, batch, p1, psum, pmax);

    k_pred <<<(NG + 3) / 4, 256, 0, stream>>>(psum, pmax, pcnt, Wp1, bp1, Wp2, bp2, out, NG);
}

// Round 5
// 316.793 us; speedup vs baseline: 3.1489x; 1.0327x over previous
//
#include <hip/hip_runtime.h>

#define NN 100000
#define NE 1000000
#define NG 2048
#define NBLK 98        // ceil(NN/1024)
#define CSRCAP 2500000 // worst-case padded CSR: sum(max(16,ceil(d/8)*8)) <= 2.5M

__device__ __forceinline__ float rl(float v, int k) {
    return __int_as_float(__builtin_amdgcn_readlane(__float_as_int(v), k));
}
__device__ __forceinline__ int rfl(int v) { return __builtin_amdgcn_readfirstlane(v); }

// padded degree: 0 stays 0; else round up to multiple of 8, min 16
#define PDEG(c) ((c) == 0 ? 0 : max(16, ((c) + 7) & ~7))

// ---------------- graph preprocessing ----------------

__global__ void k_cnt(const int* __restrict__ dst, int* __restrict__ cnt,
                      const int* __restrict__ batch, int* __restrict__ pcnt) {
    int i = blockIdx.x * blockDim.x + threadIdx.x;
    if (i < NE) atomicAdd(&cnt[dst[i]], 1);
    if (i < NN) atomicAdd(&pcnt[batch[i]], 1);
}

__global__ void k_scan1(const int* __restrict__ cnt, int* __restrict__ bsum, int n) {
    int t = threadIdx.x;
    int base = blockIdx.x * 1024 + t * 4;
    int4 v = {0, 0, 0, 0};
    if (base < n) v = *(const int4*)(cnt + base);  // n % 4 == 0
    int s = PDEG(v.x) + PDEG(v.y) + PDEG(v.z) + PDEG(v.w);
    #pragma unroll
    for (int off = 32; off; off >>= 1) s += __shfl_down(s, off, 64);
    __shared__ int ws[4];
    if ((t & 63) == 0) ws[t >> 6] = s;
    __syncthreads();
    if (t == 0) bsum[blockIdx.x] = ws[0] + ws[1] + ws[2] + ws[3];
}

__global__ void k_scan2(const int* __restrict__ bsum, int* __restrict__ boff, int nb) {
    __shared__ int buf[128];
    int t = threadIdx.x;
    int v = (t < nb) ? bsum[t] : 0;
    buf[t] = v;
    __syncthreads();
    for (int off = 1; off < 128; off <<= 1) {
        int u = (t >= off) ? buf[t - off] : 0;
        __syncthreads();
        buf[t] += u;
        __syncthreads();
    }
    if (t < nb) boff[t] = buf[t] - v;  // exclusive
}

__global__ void k_scan3(const int* __restrict__ cnt, const int* __restrict__ boff,
                        int* __restrict__ prp, int n) {
    int t = threadIdx.x;
    int base = blockIdx.x * 1024 + t * 4;
    int4 v = {0, 0, 0, 0};
    if (base < n) v = *(const int4*)(cnt + base);
    int p0 = PDEG(v.x), p1 = PDEG(v.y), p2 = PDEG(v.z), p3 = PDEG(v.w);
    int s = p0 + p1 + p2 + p3;
    int lane = t & 63;
    int ps = s;
    #pragma unroll
    for (int off = 1; off < 64; off <<= 1) {
        int u = __shfl_up(ps, off, 64);
        if (lane >= off) ps += u;
    }
    __shared__ int ws[4];
    if (lane == 63) ws[t >> 6] = ps;
    __syncthreads();
    int w = t >> 6;
    int woff = 0;
    for (int i = 0; i < 4; ++i) woff += (i < w) ? ws[i] : 0;
    int excl = boff[blockIdx.x] + woff + ps - s;
    if (base < n) {
        prp[base] = excl;          excl += p0;
        prp[base + 1] = excl;      excl += p1;
        prp[base + 2] = excl;      excl += p2;
        prp[base + 3] = excl;      excl += p3;
        if (base + 4 == n) prp[n] = excl;   // total padded edges
    }
}

__global__ void k_dinv(const int* __restrict__ cnt, float* __restrict__ dinv, int n) {
    int i = blockIdx.x * blockDim.x + threadIdx.x;
    if (i < n) dinv[i] = rsqrtf((float)(cnt[i] + 1));
}

// init padded CSR to the dummy zero-row id
__global__ void k_padinit(int* __restrict__ csr) {
    int i = blockIdx.x * blockDim.x + threadIdx.x;
    if (i * 4 < CSRCAP) {
        int4 v = {NN, NN, NN, NN};
        *(int4*)(csr + i * 4) = v;
    }
}

// px = x * dinv (padded row NN = 0); also zero row NN of p1/p2
__global__ void k_px(const float* __restrict__ x, const float* __restrict__ dinv,
                     float* __restrict__ px, float* __restrict__ p1, float* __restrict__ p2) {
    int nd = blockIdx.x * blockDim.x + threadIdx.x;
    if (nd < NN) {
        float dv = dinv[nd];
        #pragma unroll
        for (int j = 0; j < 9; ++j) px[nd * 9 + j] = x[nd * 9 + j] * dv;
    } else if (nd == NN) {
        #pragma unroll
        for (int j = 0; j < 9; ++j) px[NN * 9 + j] = 0.f;
        for (int j = 0; j < 64; ++j) {
            p1[(size_t)NN * 64 + j] = 0.f;
            p2[(size_t)NN * 64 + j] = 0.f;
        }
    }
}

__global__ void k_fill(const int* __restrict__ src, const int* __restrict__ dst,
                       const int* __restrict__ prp, int* __restrict__ fill,
                       int* __restrict__ csr, int E) {
    int i = blockIdx.x * blockDim.x + threadIdx.x;
    if (i < E) {
        int d = dst[i];
        int pos = prp[d] + atomicAdd(&fill[d], 1);
        csr[pos] = src[i];
    }
}

// ---------------- fused GCN layer ----------------
// relu(Agg(a.W)+b) == relu((dinv .* (p_self + sum_src p_src)) . W + b),  p = a .* dinv.
// KD=9: pin = px (pre-scaled, padded). KD=64: pin = p (pre-scaled, padded).
// Padded CSR: ids uniform (scalar s_load), padding -> zero row NN: no masks/clamps.
// Wave = 8 nodes, lane = output feature; matvec via readlane broadcast.

template <int KD, int POOL>
__global__ __launch_bounds__(256, 4)
void k_layer(const float* __restrict__ pin, const float* __restrict__ W,
             const float* __restrict__ bias, const float* __restrict__ dinv,
             const int* __restrict__ csr, const int* __restrict__ prp,
             const int* __restrict__ batch,
             float* __restrict__ pout, float* __restrict__ psum,
             float* __restrict__ pmax) {
    __shared__ float Ws[KD * 64];
    int tid = threadIdx.x;
    for (int i = tid; i < KD * 64; i += 256) Ws[i] = W[i];
    __syncthreads();
    int f = tid & 63;
    int wv = tid >> 6;
    int n0 = (blockIdx.x * 4 + wv) * 8;           // NN == 3125*32: no tail
    int fi = (KD < 64) ? ((f < KD) ? f : (KD - 1)) : f;

    float q0, q1, q2, q3, q4, q5, q6, q7;

#define CHUNK(E0) { \
    int s0 = csr[(E0) + 0], s1 = csr[(E0) + 1], s2 = csr[(E0) + 2], s3 = csr[(E0) + 3]; \
    int s4 = csr[(E0) + 4], s5 = csr[(E0) + 5], s6 = csr[(E0) + 6], s7 = csr[(E0) + 7]; \
    a0 += pin[(size_t)s0 * KD + fi]; a1 += pin[(size_t)s1 * KD + fi]; \
    a2 += pin[(size_t)s2 * KD + fi]; a3 += pin[(size_t)s3 * KD + fi]; \
    a0 += pin[(size_t)s4 * KD + fi]; a1 += pin[(size_t)s5 * KD + fi]; \
    a2 += pin[(size_t)s6 * KD + fi]; a3 += pin[(size_t)s7 * KD + fi]; \
}

#define GATHER(Q, J) { \
    int nd = n0 + (J); \
    int pbeg = rfl(prp[nd]); \
    int pend = rfl(prp[nd + 1]); \
    float self = pin[(size_t)nd * KD + fi]; \
    float a0 = 0.f, a1 = 0.f, a2 = 0.f, a3 = 0.f; \
    if (pbeg != pend) { \
        CHUNK(pbeg)          /* pdeg >= 16 guaranteed when deg >= 1 */ \
        CHUNK(pbeg + 8) \
        for (int e = pbeg + 16; e < pend; e += 8) CHUNK(e) \
    } \
    Q = (self + ((a0 + a1) + (a2 + a3))) * dinv[nd]; \
}
    GATHER(q0, 0) GATHER(q1, 1) GATHER(q2, 2) GATHER(q3, 3)
    GATHER(q4, 4) GATHER(q5, 5) GATHER(q6, 6) GATHER(q7, 7)
#undef GATHER
#undef CHUNK

    float bv = bias[f];
    float o0 = bv, o1 = bv, o2 = bv, o3 = bv, o4 = bv, o5 = bv, o6 = bv, o7 = bv;
    #pragma unroll
    for (int k = 0; k < KD; ++k) {
        float wsv = Ws[k * 64 + f];               // lane=f -> bank f%32: conflict-free
        o0 = fmaf(rl(q0, k), wsv, o0);
        o1 = fmaf(rl(q1, k), wsv, o1);
        o2 = fmaf(rl(q2, k), wsv, o2);
        o3 = fmaf(rl(q3, k), wsv, o3);
        o4 = fmaf(rl(q4, k), wsv, o4);
        o5 = fmaf(rl(q5, k), wsv, o5);
        o6 = fmaf(rl(q6, k), wsv, o6);
        o7 = fmaf(rl(q7, k), wsv, o7);
    }

    if (POOL == 0) {
#define STORE(O, J) pout[(size_t)(n0 + (J)) * 64 + f] = fmaxf(O, 0.f) * dinv[n0 + (J)];
        STORE(o0, 0) STORE(o1, 1) STORE(o2, 2) STORE(o3, 3)
        STORE(o4, 4) STORE(o5, 5) STORE(o6, 6) STORE(o7, 7)
#undef STORE
    } else {
        int g = batch[n0];
        float sum = 0.f, mx = 0.f;
#define ACCP(O, J) { \
    float r = fmaxf(O, 0.f); \
    int gj = batch[n0 + (J)]; \
    if (gj != g) { \
        atomicAdd(&psum[g * 64 + f], sum); \
        atomicMax((int*)&pmax[g * 64 + f], __float_as_int(mx)); \
        g = gj; sum = 0.f; mx = 0.f; \
    } \
    sum += r; mx = fmaxf(mx, r); \
}
        ACCP(o0, 0) ACCP(o1, 1) ACCP(o2, 2) ACCP(o3, 3)
        ACCP(o4, 4) ACCP(o5, 5) ACCP(o6, 6) ACCP(o7, 7)
#undef ACCP
        atomicAdd(&psum[g * 64 + f], sum);
        atomicMax((int*)&pmax[g * 64 + f], __float_as_int(mx));  // relu => mx >= 0
    }
}

// ---------------- predictor MLP ----------------

__global__ void k_pred(const float* __restrict__ psum, const float* __restrict__ pmax,
                       const int* __restrict__ pcnt,
                       const float* __restrict__ Wp1, const float* __restrict__ bp1,
                       const float* __restrict__ Wp2, const float* __restrict__ bp2,
                       float* __restrict__ out, int G) {
    __shared__ float gs[4][128];
    int tid = threadIdx.x;
    int li = tid >> 6;
    int lane = tid & 63;
    int gi = blockIdx.x * 4 + li;
    if (gi < G) {
        float c = fmaxf((float)pcnt[gi], 1.0f);
        gs[li][lane] = psum[gi * 64 + lane] / c;
        gs[li][64 + lane] = pmax[gi * 64 + lane];
    }
    __syncthreads();
    if (gi >= G) return;
    float acc = bp1[lane];
    #pragma unroll
    for (int k = 0; k < 128; ++k) acc += gs[li][k] * Wp1[k * 64 + lane];
    acc = fmaxf(acc, 0.f);
    float r = acc * Wp2[lane];
    #pragma unroll
    for (int off = 32; off; off >>= 1) r += __shfl_down(r, off, 64);
    if (lane == 0) out[gi] = r + bp2[0];
}

// ---------------- launch ----------------

extern "C" void kernel_launch(void* const* d_in, const int* in_sizes, int n_in,
                              void* d_out, int out_size, void* d_ws, size_t ws_size,
                              hipStream_t stream) {
    const float* x    = (const float*)d_in[0];
    const int*   esrc = (const int*)d_in[1];
    const int*   edst = (const int*)d_in[2];
    const int*   batch= (const int*)d_in[3];
    const float* W1 = (const float*)d_in[4];  const float* b1 = (const float*)d_in[5];
    const float* W2 = (const float*)d_in[6];  const float* b2 = (const float*)d_in[7];
    const float* W3 = (const float*)d_in[8];  const float* b3 = (const float*)d_in[9];
    const float* Wp1= (const float*)d_in[10]; const float* bp1= (const float*)d_in[11];
    const float* Wp2= (const float*)d_in[12]; const float* bp2= (const float*)d_in[13];
    float* out = (float*)d_out;

    char* ws = (char*)d_ws;
    // zero-init region (contiguous): [cnt][fill][psum][pmax][pcnt]
    int*   cnt     = (int*)  (ws + 0);          // N ints
    int*   fill    = (int*)  (ws + 400000);     // N ints
    float* psum    = (float*)(ws + 800000);     // G*64 floats
    float* pmax    = (float*)(ws + 1324288);    // G*64 floats
    int*   pcnt    = (int*)  (ws + 1848576);    // G ints
    const size_t ZBYTES = 1856768;
    float* dinv    = (float*)(ws + 1856768);    // N floats
    int*   prp     = (int*)  (ws + 2256768);    // N+1 ints (padded row_ptr)
    int*   bsum    = (int*)  (ws + 2656896);    // 128 ints
    int*   boff    = (int*)  (ws + 2657408);    // 128 ints
    int*   csr_pad = (int*)  (ws + 2657920);    // CSRCAP ints -> ends 12657920
    float* p1      = (float*)(ws + 12657920);   // (N+1)*64 floats -> ends 38258176
    float* p2      = (float*)(ws + 38258176);   // (N+1)*64 floats -> ends 63858432
    float* px      = (float*)(ws + 38258176);   // (N+1)*9 floats, overlaid in p2 (dead after layer 1)

    hipMemsetAsync(ws, 0, ZBYTES, stream);

    k_cnt    <<<(NE + 255) / 256, 256, 0, stream>>>(edst, cnt, batch, pcnt);
    k_scan1  <<<NBLK, 256, 0, stream>>>(cnt, bsum, NN);
    k_scan2  <<<1, 128, 0, stream>>>(bsum, boff, NBLK);
    k_scan3  <<<NBLK, 256, 0, stream>>>(cnt, boff, prp, NN);
    k_dinv   <<<(NN + 255) / 256, 256, 0, stream>>>(cnt, dinv, NN);
    k_padinit<<<(CSRCAP / 4 + 255) / 256, 256, 0, stream>>>(csr_pad);
    k_px     <<<(NN + 256) / 256, 256, 0, stream>>>(x, dinv, px, p1, p2);
    k_fill   <<<(NE + 255) / 256, 256, 0, stream>>>(esrc, edst, prp, fill, csr_pad, NE);

    int nbl = NN / 32;  // 3125, exact
    k_layer<9, 0><<<nbl, 256, 0, stream>>>(px, W1, b1, dinv, csr_pad, prp, batch, p1, psum, pmax);
    k_layer<64, 0><<<nbl, 256, 0, stream>>>(p1, W2, b2, dinv, csr_pad, prp, batch, p2, psum, pmax);
    k_layer<64, 1><<<nbl, 256, 0, stream>>>(p2, W3, b3, dinv, csr_pad, prp, batch, p1, psum, pmax);

    k_pred <<<(NG + 3) / 4, 256, 0, stream>>>(psum, pmax, pcnt, Wp1, bp1, Wp2, bp2, out, NG);
}

// Round 6
// 297.633 us; speedup vs baseline: 3.3516x; 1.0644x over previous
//
#include <hip/hip_runtime.h>

#define NN 100000
#define NE 1000000
#define NG 2048
#define NBLK 98        // ceil(NN/1024)
#define CSRCAP 1800000 // sum(ceil(d/8)*8) <= E + 7*N = 1.7M

__device__ __forceinline__ float rl(float v, int k) {
    return __int_as_float(__builtin_amdgcn_readlane(__float_as_int(v), k));
}
__device__ __forceinline__ int rfl(int v) { return __builtin_amdgcn_readfirstlane(v); }

// padded degree: round up to multiple of 8 (0 stays 0)
#define PDEG(c) (((c) + 7) & ~7)

// ---------------- graph preprocessing ----------------

// degree count; atomic return value = this edge's slot within its dst list (ticket).
// also per-graph node count.
__global__ void k_cnt(const int* __restrict__ dst, int* __restrict__ cnt,
                      int* __restrict__ ticket,
                      const int* __restrict__ batch, int* __restrict__ pcnt) {
    int i = blockIdx.x * blockDim.x + threadIdx.x;
    if (i < NE) ticket[i] = atomicAdd(&cnt[dst[i]], 1);
    if (i < NN) atomicAdd(&pcnt[batch[i]], 1);
}

// per-block (1024 nodes) padded-degree sums; fused: dinv + px = x*dinv + zero row NN.
__global__ void k_scan1(const int* __restrict__ cnt, int* __restrict__ bsum,
                        const float* __restrict__ x, float* __restrict__ dinv,
                        float* __restrict__ px, float* __restrict__ p1,
                        float* __restrict__ p2) {
    int t = threadIdx.x;
    int base = blockIdx.x * 1024 + t * 4;
    int4 v = {0, 0, 0, 0};
    if (base < NN) v = *(const int4*)(cnt + base);  // NN % 4 == 0
    int s = PDEG(v.x) + PDEG(v.y) + PDEG(v.z) + PDEG(v.w);
    #pragma unroll
    for (int off = 32; off; off >>= 1) s += __shfl_down(s, off, 64);
    __shared__ int ws[4];
    if ((t & 63) == 0) ws[t >> 6] = s;
    __syncthreads();
    if (t == 0) bsum[blockIdx.x] = ws[0] + ws[1] + ws[2] + ws[3];

    if (base < NN) {
        int c[4] = {v.x, v.y, v.z, v.w};
        #pragma unroll
        for (int j2 = 0; j2 < 4; ++j2) {
            int nd = base + j2;
            float dv = rsqrtf((float)(c[j2] + 1));   // +1: self-loop
            dinv[nd] = dv;
            #pragma unroll
            for (int j = 0; j < 9; ++j) px[nd * 9 + j] = x[nd * 9 + j] * dv;
        }
    } else if (base == NN) {   // zero dummy row NN of px / p1 / p2
        #pragma unroll
        for (int j = 0; j < 9; ++j) px[NN * 9 + j] = 0.f;
        for (int j = 0; j < 64; ++j) {
            p1[(size_t)NN * 64 + j] = 0.f;
            p2[(size_t)NN * 64 + j] = 0.f;
        }
    }
}

__global__ void k_scan2(const int* __restrict__ bsum, int* __restrict__ boff, int nb) {
    __shared__ int buf[128];
    int t = threadIdx.x;
    int v = (t < nb) ? bsum[t] : 0;
    buf[t] = v;
    __syncthreads();
    for (int off = 1; off < 128; off <<= 1) {
        int u = (t >= off) ? buf[t - off] : 0;
        __syncthreads();
        buf[t] += u;
        __syncthreads();
    }
    if (t < nb) boff[t] = buf[t] - v;  // exclusive
}

__global__ void k_scan3(const int* __restrict__ cnt, const int* __restrict__ boff,
                        int* __restrict__ prp, int n) {
    int t = threadIdx.x;
    int base = blockIdx.x * 1024 + t * 4;
    int4 v = {0, 0, 0, 0};
    if (base < n) v = *(const int4*)(cnt + base);
    int p0 = PDEG(v.x), p1 = PDEG(v.y), p2 = PDEG(v.z), p3 = PDEG(v.w);
    int s = p0 + p1 + p2 + p3;
    int lane = t & 63;
    int ps = s;
    #pragma unroll
    for (int off = 1; off < 64; off <<= 1) {
        int u = __shfl_up(ps, off, 64);
        if (lane >= off) ps += u;
    }
    __shared__ int ws[4];
    if (lane == 63) ws[t >> 6] = ps;
    __syncthreads();
    int w = t >> 6;
    int woff = 0;
    for (int i = 0; i < 4; ++i) woff += (i < w) ? ws[i] : 0;
    int excl = boff[blockIdx.x] + woff + ps - s;
    if (base < n) {
        prp[base] = excl;          excl += p0;
        prp[base + 1] = excl;      excl += p1;
        prp[base + 2] = excl;      excl += p2;
        prp[base + 3] = excl;      excl += p3;
        if (base + 4 == n) prp[n] = excl;   // total padded slots
    }
}

// init padded CSR to the dummy zero-row id
__global__ void k_padinit(int* __restrict__ csr) {
    int i = blockIdx.x * blockDim.x + threadIdx.x;
    if (i * 4 < CSRCAP) {
        int4 v = {NN, NN, NN, NN};
        *(int4*)(csr + i * 4) = v;
    }
}

// atomic-free CSR fill using tickets
__global__ void k_fill(const int* __restrict__ src, const int* __restrict__ dst,
                       const int* __restrict__ prp, const int* __restrict__ ticket,
                       int* __restrict__ csr, int E) {
    int i = blockIdx.x * blockDim.x + threadIdx.x;
    if (i < E) csr[prp[dst[i]] + ticket[i]] = src[i];
}

// ---------------- fused GCN layer ----------------
// relu(Agg(a.W)+b) == relu((dinv .* (p_self + sum_src p_src)) . W + b),  p = a .* dinv.
// Padded CSR: ids wave-uniform (scalar loads), padding -> zero row NN: no masks.
// Wave = 8 nodes, lane = output feature; matvec via readlane broadcast.

template <int KD, int POOL>
__global__ __launch_bounds__(256, 8)
void k_layer(const float* __restrict__ pin, const float* __restrict__ W,
             const float* __restrict__ bias, const float* __restrict__ dinv,
             const int* __restrict__ csr, const int* __restrict__ prp,
             const int* __restrict__ batch,
             float* __restrict__ pout, float* __restrict__ psum,
             float* __restrict__ pmax) {
    __shared__ float Ws[KD * 64];
    int tid = threadIdx.x;
    for (int i = tid; i < KD * 64; i += 256) Ws[i] = W[i];
    __syncthreads();
    int f = tid & 63;
    int wv = tid >> 6;
    int n0 = (blockIdx.x * 4 + wv) * 8;           // NN == 3125*32: no tail
    int fi = (KD < 64) ? ((f < KD) ? f : (KD - 1)) : f;

    float q0, q1, q2, q3, q4, q5, q6, q7;

#define CHUNK(E0) { \
    int s0 = csr[(E0) + 0], s1 = csr[(E0) + 1], s2 = csr[(E0) + 2], s3 = csr[(E0) + 3]; \
    int s4 = csr[(E0) + 4], s5 = csr[(E0) + 5], s6 = csr[(E0) + 6], s7 = csr[(E0) + 7]; \
    a0 += pin[(size_t)s0 * KD + fi]; a1 += pin[(size_t)s1 * KD + fi]; \
    a2 += pin[(size_t)s2 * KD + fi]; a3 += pin[(size_t)s3 * KD + fi]; \
    a0 += pin[(size_t)s4 * KD + fi]; a1 += pin[(size_t)s5 * KD + fi]; \
    a2 += pin[(size_t)s6 * KD + fi]; a3 += pin[(size_t)s7 * KD + fi]; \
}

#define GATHER(Q, J) { \
    int nd = n0 + (J); \
    int pbeg = rfl(prp[nd]); \
    int pend = rfl(prp[nd + 1]); \
    float self = pin[(size_t)nd * KD + fi]; \
    float a0 = 0.f, a1 = 0.f, a2 = 0.f, a3 = 0.f; \
    if (pbeg != pend) { \
        CHUNK(pbeg)          /* pdeg >= 8 whenever deg >= 1 */ \
        for (int e = pbeg + 8; e < pend; e += 8) CHUNK(e) \
    } \
    Q = (self + ((a0 + a1) + (a2 + a3))) * dinv[nd]; \
}
    GATHER(q0, 0) GATHER(q1, 1) GATHER(q2, 2) GATHER(q3, 3)
    GATHER(q4, 4) GATHER(q5, 5) GATHER(q6, 6) GATHER(q7, 7)
#undef GATHER
#undef CHUNK

    float bv = bias[f];
    float o0 = bv, o1 = bv, o2 = bv, o3 = bv, o4 = bv, o5 = bv, o6 = bv, o7 = bv;
    #pragma unroll
    for (int k = 0; k < KD; ++k) {
        float wsv = Ws[k * 64 + f];               // lane=f -> bank f%32: conflict-free
        o0 = fmaf(rl(q0, k), wsv, o0);
        o1 = fmaf(rl(q1, k), wsv, o1);
        o2 = fmaf(rl(q2, k), wsv, o2);
        o3 = fmaf(rl(q3, k), wsv, o3);
        o4 = fmaf(rl(q4, k), wsv, o4);
        o5 = fmaf(rl(q5, k), wsv, o5);
        o6 = fmaf(rl(q6, k), wsv, o6);
        o7 = fmaf(rl(q7, k), wsv, o7);
    }

    if (POOL == 0) {
#define STORE(O, J) pout[(size_t)(n0 + (J)) * 64 + f] = fmaxf(O, 0.f) * dinv[n0 + (J)];
        STORE(o0, 0) STORE(o1, 1) STORE(o2, 2) STORE(o3, 3)
        STORE(o4, 4) STORE(o5, 5) STORE(o6, 6) STORE(o7, 7)
#undef STORE
    } else {
        int g = batch[n0];
        float sum = 0.f, mx = 0.f;
#define ACCP(O, J) { \
    float r = fmaxf(O, 0.f); \
    int gj = batch[n0 + (J)]; \
    if (gj != g) { \
        atomicAdd(&psum[g * 64 + f], sum); \
        atomicMax((int*)&pmax[g * 64 + f], __float_as_int(mx)); \
        g = gj; sum = 0.f; mx = 0.f; \
    } \
    sum += r; mx = fmaxf(mx, r); \
}
        ACCP(o0, 0) ACCP(o1, 1) ACCP(o2, 2) ACCP(o3, 3)
        ACCP(o4, 4) ACCP(o5, 5) ACCP(o6, 6) ACCP(o7, 7)
#undef ACCP
        atomicAdd(&psum[g * 64 + f], sum);
        atomicMax((int*)&pmax[g * 64 + f], __float_as_int(mx));  // relu => mx >= 0
    }
}

// ---------------- predictor MLP ----------------

__global__ void k_pred(const float* __restrict__ psum, const float* __restrict__ pmax,
                       const int* __restrict__ pcnt,
                       const float* __restrict__ Wp1, const float* __restrict__ bp1,
                       const float* __restrict__ Wp2, const float* __restrict__ bp2,
                       float* __restrict__ out, int G) {
    __shared__ float gs[4][128];
    int tid = threadIdx.x;
    int li = tid >> 6;
    int lane = tid & 63;
    int gi = blockIdx.x * 4 + li;
    if (gi < G) {
        float c = fmaxf((float)pcnt[gi], 1.0f);
        gs[li][lane] = psum[gi * 64 + lane] / c;
        gs[li][64 + lane] = pmax[gi * 64 + lane];
    }
    __syncthreads();
    if (gi >= G) return;
    float acc = bp1[lane];
    #pragma unroll
    for (int k = 0; k < 128; ++k) acc += gs[li][k] * Wp1[k * 64 + lane];
    acc = fmaxf(acc, 0.f);
    float r = acc * Wp2[lane];
    #pragma unroll
    for (int off = 32; off; off >>= 1) r += __shfl_down(r, off, 64);
    if (lane == 0) out[gi] = r + bp2[0];
}

// ---------------- launch ----------------

extern "C" void kernel_launch(void* const* d_in, const int* in_sizes, int n_in,
                              void* d_out, int out_size, void* d_ws, size_t ws_size,
                              hipStream_t stream) {
    const float* x    = (const float*)d_in[0];
    const int*   esrc = (const int*)d_in[1];
    const int*   edst = (const int*)d_in[2];
    const int*   batch= (const int*)d_in[3];
    const float* W1 = (const float*)d_in[4];  const float* b1 = (const float*)d_in[5];
    const float* W2 = (const float*)d_in[6];  const float* b2 = (const float*)d_in[7];
    const float* W3 = (const float*)d_in[8];  const float* b3 = (const float*)d_in[9];
    const float* Wp1= (const float*)d_in[10]; const float* bp1= (const float*)d_in[11];
    const float* Wp2= (const float*)d_in[12]; const float* bp2= (const float*)d_in[13];
    float* out = (float*)d_out;

    char* ws = (char*)d_ws;
    // zero-init region (contiguous): [cnt][psum][pmax][pcnt]
    int*   cnt     = (int*)  (ws + 0);          // N ints
    float* psum    = (float*)(ws + 400000);     // G*64 floats -> 924288
    float* pmax    = (float*)(ws + 924288);     // G*64 floats -> 1448576
    int*   pcnt    = (int*)  (ws + 1448576);    // G ints -> 1456768
    const size_t ZBYTES = 1456768;
    float* dinv    = (float*)(ws + 1456768);    // N floats -> 1856768
    int*   prp     = (int*)  (ws + 1856768);    // N+1 ints -> 2256896 (pad to 2257408)
    int*   bsum    = (int*)  (ws + 2257408);    // 128 ints -> 2257920
    int*   boff    = (int*)  (ws + 2257920);    // 128 ints -> 2258432
    int*   csr_pad = (int*)  (ws + 2258432);    // CSRCAP ints -> 9458432
    float* p1      = (float*)(ws + 9458432);    // (N+1)*64 floats -> 35058688
    float* p2      = (float*)(ws + 35058688);   // (N+1)*64 floats -> 60658944
    int*   ticket  = (int*)  (ws + 9458432);    // E ints, overlays p1[0..1M) (dead before layer1)
    float* px      = (float*)(ws + 35058688);   // (N+1)*9 floats, overlays p2 (dead after layer1)

    hipMemsetAsync(ws, 0, ZBYTES, stream);

    k_cnt    <<<(NE + 255) / 256, 256, 0, stream>>>(edst, cnt, ticket, batch, pcnt);
    k_scan1  <<<NBLK, 256, 0, stream>>>(cnt, bsum, x, dinv, px, p1, p2);
    k_scan2  <<<1, 128, 0, stream>>>(bsum, boff, NBLK);
    k_scan3  <<<NBLK, 256, 0, stream>>>(cnt, boff, prp, NN);
    k_padinit<<<(CSRCAP / 4 + 255) / 256, 256, 0, stream>>>(csr_pad);
    k_fill   <<<(NE + 255) / 256, 256, 0, stream>>>(esrc, edst, prp, ticket, csr_pad, NE);

    int nbl = NN / 32;  // 3125, exact
    k_layer<9, 0><<<nbl, 256, 0, stream>>>(px, W1, b1, dinv, csr_pad, prp, batch, p1, psum, pmax);
    k_layer<64, 0><<<nbl, 256, 0, stream>>>(p1, W2, b2, dinv, csr_pad, prp, batch, p2, psum, pmax);
    k_layer<64, 1><<<nbl, 256, 0, stream>>>(p2, W3, b3, dinv, csr_pad, prp, batch, p1, psum, pmax);

    k_pred <<<(NG + 3) / 4, 256, 0, stream>>>(psum, pmax, pcnt, Wp1, bp1, Wp2, bp2, out, NG);
}

// Round 7
// 275.670 us; speedup vs baseline: 3.6187x; 1.0797x over previous
//
#include <hip/hip_runtime.h>

#define NN 100000
#define NE 1000000
#define NG 2048
#define NBLK 98        // ceil(NN/1024)
#define CSRCAP 1800000 // sum(ceil(d/8)*8) <= E + 7*N = 1.7M

__device__ __forceinline__ float rl(float v, int k) {
    return __int_as_float(__builtin_amdgcn_readlane(__float_as_int(v), k));
}
__device__ __forceinline__ int rfl(int v) { return __builtin_amdgcn_readfirstlane(v); }

// padded degree: round up to multiple of 8 (0 stays 0)
#define PDEG(c) (((c) + 7) & ~7)

// ---------------- graph preprocessing ----------------

// degree count; atomic return value = this edge's slot within its dst list (ticket).
// also per-graph node count.
__global__ void k_cnt(const int* __restrict__ dst, int* __restrict__ cnt,
                      int* __restrict__ ticket,
                      const int* __restrict__ batch, int* __restrict__ pcnt) {
    int i = blockIdx.x * blockDim.x + threadIdx.x;
    if (i < NE) ticket[i] = atomicAdd(&cnt[dst[i]], 1);
    if (i < NN) atomicAdd(&pcnt[batch[i]], 1);
}

// per-block (1024 nodes) padded-degree sums; fused: dinv + px = x*dinv + zero row NN.
__global__ void k_scan1(const int* __restrict__ cnt, int* __restrict__ bsum,
                        const float* __restrict__ x, float* __restrict__ dinv,
                        float* __restrict__ px, float* __restrict__ p1,
                        float* __restrict__ p2) {
    int t = threadIdx.x;
    int base = blockIdx.x * 1024 + t * 4;
    int4 v = {0, 0, 0, 0};
    if (base < NN) v = *(const int4*)(cnt + base);  // NN % 4 == 0
    int s = PDEG(v.x) + PDEG(v.y) + PDEG(v.z) + PDEG(v.w);
    #pragma unroll
    for (int off = 32; off; off >>= 1) s += __shfl_down(s, off, 64);
    __shared__ int ws[4];
    if ((t & 63) == 0) ws[t >> 6] = s;
    __syncthreads();
    if (t == 0) bsum[blockIdx.x] = ws[0] + ws[1] + ws[2] + ws[3];

    if (base < NN) {
        int c[4] = {v.x, v.y, v.z, v.w};
        #pragma unroll
        for (int j2 = 0; j2 < 4; ++j2) {
            int nd = base + j2;
            float dv = rsqrtf((float)(c[j2] + 1));   // +1: self-loop
            dinv[nd] = dv;
            #pragma unroll
            for (int j = 0; j < 9; ++j) px[nd * 9 + j] = x[nd * 9 + j] * dv;
        }
    } else if (base == NN) {   // zero dummy row NN of px / p1 / p2
        #pragma unroll
        for (int j = 0; j < 9; ++j) px[NN * 9 + j] = 0.f;
        for (int j = 0; j < 64; ++j) {
            p1[(size_t)NN * 64 + j] = 0.f;
            p2[(size_t)NN * 64 + j] = 0.f;
        }
    }
}

__global__ void k_scan2(const int* __restrict__ bsum, int* __restrict__ boff, int nb) {
    __shared__ int buf[128];
    int t = threadIdx.x;
    int v = (t < nb) ? bsum[t] : 0;
    buf[t] = v;
    __syncthreads();
    for (int off = 1; off < 128; off <<= 1) {
        int u = (t >= off) ? buf[t - off] : 0;
        __syncthreads();
        buf[t] += u;
        __syncthreads();
    }
    if (t < nb) boff[t] = buf[t] - v;  // exclusive
}

__global__ void k_scan3(const int* __restrict__ cnt, const int* __restrict__ boff,
                        int* __restrict__ prp, int n) {
    int t = threadIdx.x;
    int base = blockIdx.x * 1024 + t * 4;
    int4 v = {0, 0, 0, 0};
    if (base < n) v = *(const int4*)(cnt + base);
    int p0 = PDEG(v.x), p1 = PDEG(v.y), p2 = PDEG(v.z), p3 = PDEG(v.w);
    int s = p0 + p1 + p2 + p3;
    int lane = t & 63;
    int ps = s;
    #pragma unroll
    for (int off = 1; off < 64; off <<= 1) {
        int u = __shfl_up(ps, off, 64);
        if (lane >= off) ps += u;
    }
    __shared__ int ws[4];
    if (lane == 63) ws[t >> 6] = ps;
    __syncthreads();
    int w = t >> 6;
    int woff = 0;
    for (int i = 0; i < 4; ++i) woff += (i < w) ? ws[i] : 0;
    int excl = boff[blockIdx.x] + woff + ps - s;
    if (base < n) {
        prp[base] = excl;          excl += p0;
        prp[base + 1] = excl;      excl += p1;
        prp[base + 2] = excl;      excl += p2;
        prp[base + 3] = excl;      excl += p3;
        if (base + 4 == n) prp[n] = excl;   // total padded slots
    }
}

// init padded CSR to the dummy zero-row id
__global__ void k_padinit(int* __restrict__ csr) {
    int i = blockIdx.x * blockDim.x + threadIdx.x;
    if (i * 4 < CSRCAP) {
        int4 v = {NN, NN, NN, NN};
        *(int4*)(csr + i * 4) = v;
    }
}

// atomic-free CSR fill using tickets
__global__ void k_fill(const int* __restrict__ src, const int* __restrict__ dst,
                       const int* __restrict__ prp, const int* __restrict__ ticket,
                       int* __restrict__ csr, int E) {
    int i = blockIdx.x * blockDim.x + threadIdx.x;
    if (i < E) csr[prp[dst[i]] + ticket[i]] = src[i];
}

// ---------------- fused GCN layer ----------------
// relu(Agg(a.W)+b) == relu((dinv .* (p_self + sum_src p_src)) . W + b),  p = a .* dinv.
// Padded CSR: ids wave-uniform (scalar loads), padding -> zero row NN: no masks.
// Wave = 8 nodes, lane = output feature; matvec via readlane broadcast.
// launch_bounds(256,6): VGPR cap 85 -> deep load pipelining AND ~75% occupancy.

template <int KD, int POOL>
__global__ __launch_bounds__(256, 6)
void k_layer(const float* __restrict__ pin, const float* __restrict__ W,
             const float* __restrict__ bias, const float* __restrict__ dinv,
             const int* __restrict__ csr, const int* __restrict__ prp,
             const int* __restrict__ batch,
             float* __restrict__ pout, float* __restrict__ psum,
             float* __restrict__ pmax) {
    __shared__ float Ws[KD * 64];
    int tid = threadIdx.x;
    for (int i = tid; i < KD * 64; i += 256) Ws[i] = W[i];
    __syncthreads();
    int f = tid & 63;
    int wv = tid >> 6;
    int n0 = (blockIdx.x * 4 + wv) * 8;           // NN == 3125*32: no tail
    int fi = (KD < 64) ? ((f < KD) ? f : (KD - 1)) : f;

    float q0, q1, q2, q3, q4, q5, q6, q7;

#define CHUNK(E0) { \
    int s0 = csr[(E0) + 0], s1 = csr[(E0) + 1], s2 = csr[(E0) + 2], s3 = csr[(E0) + 3]; \
    int s4 = csr[(E0) + 4], s5 = csr[(E0) + 5], s6 = csr[(E0) + 6], s7 = csr[(E0) + 7]; \
    a0 += pin[(size_t)s0 * KD + fi]; a1 += pin[(size_t)s1 * KD + fi]; \
    a2 += pin[(size_t)s2 * KD + fi]; a3 += pin[(size_t)s3 * KD + fi]; \
    a0 += pin[(size_t)s4 * KD + fi]; a1 += pin[(size_t)s5 * KD + fi]; \
    a2 += pin[(size_t)s6 * KD + fi]; a3 += pin[(size_t)s7 * KD + fi]; \
}

// straight-line for pdeg in {8,16,24} (~99% of Poisson(10) nodes), loop tail after.
#define GATHER(Q, J) { \
    int nd = n0 + (J); \
    int pbeg = rfl(prp[nd]); \
    int pend = rfl(prp[nd + 1]); \
    float self = pin[(size_t)nd * KD + fi]; \
    float a0 = 0.f, a1 = 0.f, a2 = 0.f, a3 = 0.f; \
    if (pbeg != pend) { \
        CHUNK(pbeg) \
        if (pbeg + 8 < pend) { \
            CHUNK(pbeg + 8) \
            if (pbeg + 16 < pend) { \
                CHUNK(pbeg + 16) \
                for (int e = pbeg + 24; e < pend; e += 8) CHUNK(e) \
            } \
        } \
    } \
    Q = (self + ((a0 + a1) + (a2 + a3))) * dinv[nd]; \
}
    GATHER(q0, 0) GATHER(q1, 1) GATHER(q2, 2) GATHER(q3, 3)
    GATHER(q4, 4) GATHER(q5, 5) GATHER(q6, 6) GATHER(q7, 7)
#undef GATHER
#undef CHUNK

    float bv = bias[f];
    float o0 = bv, o1 = bv, o2 = bv, o3 = bv, o4 = bv, o5 = bv, o6 = bv, o7 = bv;
    #pragma unroll
    for (int k = 0; k < KD; ++k) {
        float wsv = Ws[k * 64 + f];               // lane=f -> bank f%32: conflict-free
        o0 = fmaf(rl(q0, k), wsv, o0);
        o1 = fmaf(rl(q1, k), wsv, o1);
        o2 = fmaf(rl(q2, k), wsv, o2);
        o3 = fmaf(rl(q3, k), wsv, o3);
        o4 = fmaf(rl(q4, k), wsv, o4);
        o5 = fmaf(rl(q5, k), wsv, o5);
        o6 = fmaf(rl(q6, k), wsv, o6);
        o7 = fmaf(rl(q7, k), wsv, o7);
    }

    if (POOL == 0) {
#define STORE(O, J) pout[(size_t)(n0 + (J)) * 64 + f] = fmaxf(O, 0.f) * dinv[n0 + (J)];
        STORE(o0, 0) STORE(o1, 1) STORE(o2, 2) STORE(o3, 3)
        STORE(o4, 4) STORE(o5, 5) STORE(o6, 6) STORE(o7, 7)
#undef STORE
    } else {
        int g = batch[n0];
        float sum = 0.f, mx = 0.f;
#define ACCP(O, J) { \
    float r = fmaxf(O, 0.f); \
    int gj = batch[n0 + (J)]; \
    if (gj != g) { \
        atomicAdd(&psum[g * 64 + f], sum); \
        atomicMax((int*)&pmax[g * 64 + f], __float_as_int(mx)); \
        g = gj; sum = 0.f; mx = 0.f; \
    } \
    sum += r; mx = fmaxf(mx, r); \
}
        ACCP(o0, 0) ACCP(o1, 1) ACCP(o2, 2) ACCP(o3, 3)
        ACCP(o4, 4) ACCP(o5, 5) ACCP(o6, 6) ACCP(o7, 7)
#undef ACCP
        atomicAdd(&psum[g * 64 + f], sum);
        atomicMax((int*)&pmax[g * 64 + f], __float_as_int(mx));  // relu => mx >= 0
    }
}

// ---------------- predictor MLP ----------------

__global__ void k_pred(const float* __restrict__ psum, const float* __restrict__ pmax,
                       const int* __restrict__ pcnt,
                       const float* __restrict__ Wp1, const float* __restrict__ bp1,
                       const float* __restrict__ Wp2, const float* __restrict__ bp2,
                       float* __restrict__ out, int G) {
    __shared__ float gs[4][128];
    int tid = threadIdx.x;
    int li = tid >> 6;
    int lane = tid & 63;
    int gi = blockIdx.x * 4 + li;
    if (gi < G) {
        float c = fmaxf((float)pcnt[gi], 1.0f);
        gs[li][lane] = psum[gi * 64 + lane] / c;
        gs[li][64 + lane] = pmax[gi * 64 + lane];
    }
    __syncthreads();
    if (gi >= G) return;
    float acc = bp1[lane];
    #pragma unroll
    for (int k = 0; k < 128; ++k) acc += gs[li][k] * Wp1[k * 64 + lane];
    acc = fmaxf(acc, 0.f);
    float r = acc * Wp2[lane];
    #pragma unroll
    for (int off = 32; off; off >>= 1) r += __shfl_down(r, off, 64);
    if (lane == 0) out[gi] = r + bp2[0];
}

// ---------------- launch ----------------

extern "C" void kernel_launch(void* const* d_in, const int* in_sizes, int n_in,
                              void* d_out, int out_size, void* d_ws, size_t ws_size,
                              hipStream_t stream) {
    const float* x    = (const float*)d_in[0];
    const int*   esrc = (const int*)d_in[1];
    const int*   edst = (const int*)d_in[2];
    const int*   batch= (const int*)d_in[3];
    const float* W1 = (const float*)d_in[4];  const float* b1 = (const float*)d_in[5];
    const float* W2 = (const float*)d_in[6];  const float* b2 = (const float*)d_in[7];
    const float* W3 = (const float*)d_in[8];  const float* b3 = (const float*)d_in[9];
    const float* Wp1= (const float*)d_in[10]; const float* bp1= (const float*)d_in[11];
    const float* Wp2= (const float*)d_in[12]; const float* bp2= (const float*)d_in[13];
    float* out = (float*)d_out;

    char* ws = (char*)d_ws;
    // zero-init region (contiguous): [cnt][psum][pmax][pcnt]
    int*   cnt     = (int*)  (ws + 0);          // N ints
    float* psum    = (float*)(ws + 400000);     // G*64 floats -> 924288
    float* pmax    = (float*)(ws + 924288);     // G*64 floats -> 1448576
    int*   pcnt    = (int*)  (ws + 1448576);    // G ints -> 1456768
    const size_t ZBYTES = 1456768;
    float* dinv    = (float*)(ws + 1456768);    // N floats -> 1856768
    int*   prp     = (int*)  (ws + 1856768);    // N+1 ints -> 2256896 (pad to 2257408)
    int*   bsum    = (int*)  (ws + 2257408);    // 128 ints -> 2257920
    int*   boff    = (int*)  (ws + 2257920);    // 128 ints -> 2258432
    int*   csr_pad = (int*)  (ws + 2258432);    // CSRCAP ints -> 9458432
    float* p1      = (float*)(ws + 9458432);    // (N+1)*64 floats -> 35058688
    float* p2      = (float*)(ws + 35058688);   // (N+1)*64 floats -> 60658944
    int*   ticket  = (int*)  (ws + 9458432);    // E ints, overlays p1[0..1M) (dead before layer1)
    float* px      = (float*)(ws + 35058688);   // (N+1)*9 floats, overlays p2 (dead after layer1)

    hipMemsetAsync(ws, 0, ZBYTES, stream);

    k_cnt    <<<(NE + 255) / 256, 256, 0, stream>>>(edst, cnt, ticket, batch, pcnt);
    k_scan1  <<<NBLK, 256, 0, stream>>>(cnt, bsum, x, dinv, px, p1, p2);
    k_scan2  <<<1, 128, 0, stream>>>(bsum, boff, NBLK);
    k_scan3  <<<NBLK, 256, 0, stream>>>(cnt, boff, prp, NN);
    k_padinit<<<(CSRCAP / 4 + 255) / 256, 256, 0, stream>>>(csr_pad);
    k_fill   <<<(NE + 255) / 256, 256, 0, stream>>>(esrc, edst, prp, ticket, csr_pad, NE);

    int nbl = NN / 32;  // 3125, exact
    k_layer<9, 0><<<nbl, 256, 0, stream>>>(px, W1, b1, dinv, csr_pad, prp, batch, p1, psum, pmax);
    k_layer<64, 0><<<nbl, 256, 0, stream>>>(p1, W2, b2, dinv, csr_pad, prp, batch, p2, psum, pmax);
    k_layer<64, 1><<<nbl, 256, 0, stream>>>(p2, W3, b3, dinv, csr_pad, prp, batch, p1, psum, pmax);

    k_pred <<<(NG + 3) / 4, 256, 0, stream>>>(psum, pmax, pcnt, Wp1, bp1, Wp2, bp2, out, NG);
}